// Round 1
// baseline (311.553 us; speedup 1.0000x reference)
//
#include <hip/hip_runtime.h>

// ---------------- CSR build ----------------

__global__ void zero_i32(int* p, int n) {
    int i = blockIdx.x * blockDim.x + threadIdx.x;
    if (i < n) p[i] = 0;
}

__global__ void hist_kernel(const int* __restrict__ dst, int E, int N, int* __restrict__ deg) {
    int i = blockIdx.x * blockDim.x + threadIdx.x;
    int Etot = E + N;
    if (i < Etot) {
        int d = (i < E) ? dst[i] : (i - E);   // self-loops appended
        atomicAdd(&deg[d], 1);
    }
}

// Single-block exclusive scan over deg[0..n-1] -> offs[0..n]; also copies to pos[].
__global__ void scan_kernel(const int* __restrict__ deg, int* __restrict__ offs,
                            int* __restrict__ pos, int n) {
    __shared__ int smem[256];
    __shared__ int carrysh;
    if (threadIdx.x == 0) carrysh = 0;
    __syncthreads();
    for (int base = 0; base < n; base += 256) {
        int i = base + threadIdx.x;
        int v = (i < n) ? deg[i] : 0;
        smem[threadIdx.x] = v;
        __syncthreads();
        for (int off = 1; off < 256; off <<= 1) {
            int t = (threadIdx.x >= off) ? smem[threadIdx.x - off] : 0;
            __syncthreads();
            smem[threadIdx.x] += t;
            __syncthreads();
        }
        int carry = carrysh;
        int excl = carry + smem[threadIdx.x] - v;
        if (i < n) { offs[i] = excl; pos[i] = excl; }
        __syncthreads();
        if (threadIdx.x == 255) carrysh = carry + smem[255];
        __syncthreads();
    }
    if (threadIdx.x == 0) offs[n] = carrysh;
}

__global__ void scatter_kernel(const int* __restrict__ srcArr, const int* __restrict__ dstArr,
                               int E, int N, int* __restrict__ pos, int* __restrict__ csr_src) {
    int i = blockIdx.x * blockDim.x + threadIdx.x;
    int Etot = E + N;
    if (i < Etot) {
        int s, d;
        if (i < E) { s = srcArr[i]; d = dstArr[i]; }
        else       { s = d = i - E; }
        int p = atomicAdd(&pos[d], 1);
        csr_src[p] = s;
    }
}

// ---------------- GEMM (x @ W) + attention dot products ----------------
// W is (128,128) row-major. a_src/a_dst flattened to 128 floats (H,128/H).
// 8 rows per block, 128 threads: thread j owns output column j.
template <int H>
__global__ void gemm_att(const float* __restrict__ x, const float* __restrict__ W,
                         const float* __restrict__ a_src, const float* __restrict__ a_dst,
                         float* __restrict__ hw, float* __restrict__ asrc,
                         float* __restrict__ adst, int N) {
    const int NB = 8;
    int n0 = blockIdx.x * NB;
    int j = threadIdx.x;   // 0..127
    __shared__ float xr[NB][128];
    __shared__ float tmp[4];
    for (int r = 0; r < NB; r++) {
        int nn = n0 + r;
        xr[r][j] = (nn < N) ? x[nn * 128 + j] : 0.f;
    }
    __syncthreads();
    float acc[NB];
#pragma unroll
    for (int r = 0; r < NB; r++) acc[r] = 0.f;
    for (int k = 0; k < 128; k++) {
        float w = W[k * 128 + j];
#pragma unroll
        for (int r = 0; r < NB; r++) acc[r] += xr[r][k] * w;
    }
    const int dh = 128 / H;
    int h = j / dh;
    float as = a_src[j];
    float ad = a_dst[j];
    for (int r = 0; r < NB; r++) {
        int nn = n0 + r;
        if (nn < N) hw[nn * 128 + j] = acc[r];
        float vs = acc[r] * as;
        float vd = acc[r] * ad;
        if (H == 4) {
            // reduce within each 32-lane group (one head)
            for (int off = 16; off >= 1; off >>= 1) {
                vs += __shfl_xor(vs, off);
                vd += __shfl_xor(vd, off);
            }
            if ((j & 31) == 0 && nn < N) { asrc[nn * 4 + h] = vs; adst[nn * 4 + h] = vd; }
        } else {
            // reduce all 128 threads: wave64 shuffle + LDS combine of 2 waves
            for (int off = 32; off >= 1; off >>= 1) {
                vs += __shfl_xor(vs, off);
                vd += __shfl_xor(vd, off);
            }
            if ((j & 63) == 0) { tmp[(j >> 6) * 2] = vs; tmp[(j >> 6) * 2 + 1] = vd; }
            __syncthreads();
            if (j == 0 && nn < N) { asrc[nn] = tmp[0] + tmp[2]; adst[nn] = tmp[1] + tmp[3]; }
            __syncthreads();
        }
    }
}

// ---------------- Fused attention softmax + aggregation, one block per dst node ----------------
// out[n,j] = ELU( (sum_e exp(leaky(asrc[s_e]+adst[n])) * hw[s_e, j]) / z + b[j] )
template <int H>
__global__ void agg(const float* __restrict__ hw, const float* __restrict__ asrc,
                    const float* __restrict__ adst, const int* __restrict__ offs,
                    const int* __restrict__ csr_src, const float* __restrict__ b,
                    float* __restrict__ y, int N) {
    int n = blockIdx.x;
    int j = threadIdx.x;  // 0..127
    int beg = offs[n], end = offs[n + 1];
    int deg = end - beg;
    __shared__ float pe[128 * H];
    __shared__ int se[128];
    __shared__ float adl[H];
    __shared__ float zsh[H];
    if (j < H) adl[j] = adst[n * H + j];
    __syncthreads();
    const int dh = 128 / H;
    int h = j / dh;
    float accv = 0.f;
    float zloc = 0.f;  // threads 0..H-1 accumulate z for head==threadIdx
    for (int base = 0; base < deg; base += 128) {
        int cnt = min(128, deg - base);
        if (j < cnt) {
            int s = csr_src[beg + base + j];
            se[j] = s;
#pragma unroll
            for (int hh = 0; hh < H; hh++) {
                float e = asrc[s * H + hh] + adl[hh];
                e = e > 0.f ? e : 0.2f * e;  // leaky_relu(0.2)
                pe[j * H + hh] = __expf(e);
            }
        }
        __syncthreads();
        for (int c = 0; c < cnt; c++) {
            accv += pe[c * H + h] * hw[se[c] * 128 + j];
        }
        if (j < H) {
            for (int c = 0; c < cnt; c++) zloc += pe[c * H + j];
        }
        __syncthreads();
    }
    if (j < H) zsh[j] = zloc;
    __syncthreads();
    float res = accv / (zsh[h] + 1e-16f) + b[j];
    y[n * 128 + j] = res > 0.f ? res : (__expf(res) - 1.0f);  // ELU
}

// ---------------- Final linear head (128 -> OUT) ----------------
__global__ void lin_kernel(const float* __restrict__ y2, const float* __restrict__ Wl,
                           const float* __restrict__ bl, float* __restrict__ out,
                           int N, int OUTC) {
    const int NB = 8;
    int n0 = blockIdx.x * NB;
    int j = threadIdx.x;  // 0..63
    __shared__ float r[NB][128];
    for (int rr = 0; rr < NB; rr++) {
        int nn = n0 + rr;
        r[rr][j]      = (nn < N) ? y2[nn * 128 + j] : 0.f;
        r[rr][j + 64] = (nn < N) ? y2[nn * 128 + j + 64] : 0.f;
    }
    __syncthreads();
    if (j < OUTC) {
        float acc[NB];
#pragma unroll
        for (int rr = 0; rr < NB; rr++) acc[rr] = bl[j];
        for (int k = 0; k < 128; k++) {
            float w = Wl[k * OUTC + j];
#pragma unroll
            for (int rr = 0; rr < NB; rr++) acc[rr] += r[rr][k] * w;
        }
        for (int rr = 0; rr < NB; rr++) {
            int nn = n0 + rr;
            if (nn < N) out[nn * OUTC + j] = acc[rr];
        }
    }
}

extern "C" void kernel_launch(void* const* d_in, const int* in_sizes, int n_in,
                              void* d_out, int out_size, void* d_ws, size_t ws_size,
                              hipStream_t stream) {
    const float* x       = (const float*)d_in[0];
    const int*   ei      = (const int*)d_in[1];
    const float* W1      = (const float*)d_in[2];
    const float* a_src1  = (const float*)d_in[3];
    const float* a_dst1  = (const float*)d_in[4];
    const float* b1      = (const float*)d_in[5];
    const float* W2      = (const float*)d_in[6];
    const float* a_src2  = (const float*)d_in[7];
    const float* a_dst2  = (const float*)d_in[8];
    const float* b2      = (const float*)d_in[9];
    const float* Wlin    = (const float*)d_in[10];
    const float* blin    = (const float*)d_in[11];
    float* out = (float*)d_out;

    const int N = in_sizes[0] / 128;     // 10000
    const int E = in_sizes[1] / 2;       // 640000
    const int OUTC = in_sizes[10] / 128; // 40
    const int Etot = E + N;
    const int* src = ei;
    const int* dst = ei + E;

    // workspace carve-up (256B aligned)
    char* w = (char*)d_ws;
    size_t off = 0;
    auto alloc = [&](size_t bytes) -> char* {
        char* p = w + off;
        off += (bytes + 255) & ~(size_t)255;
        return p;
    };
    int*   deg    = (int*)alloc((size_t)N * 4);
    int*   offs   = (int*)alloc((size_t)(N + 1) * 4);
    int*   pos    = (int*)alloc((size_t)N * 4);
    int*   csr    = (int*)alloc((size_t)Etot * 4);
    float* bufA   = (float*)alloc((size_t)N * 128 * 4);
    float* bufB   = (float*)alloc((size_t)N * 128 * 4);
    float* asrc1  = (float*)alloc((size_t)N * 4 * 4);
    float* adst1  = (float*)alloc((size_t)N * 4 * 4);
    float* asrc2  = (float*)alloc((size_t)N * 4);
    float* adst2  = (float*)alloc((size_t)N * 4);
    (void)ws_size;

    // 1. CSR build (same graph reused for both layers)
    zero_i32<<<(N + 255) / 256, 256, 0, stream>>>(deg, N);
    hist_kernel<<<(Etot + 255) / 256, 256, 0, stream>>>(dst, E, N, deg);
    scan_kernel<<<1, 256, 0, stream>>>(deg, offs, pos, N);
    scatter_kernel<<<(Etot + 255) / 256, 256, 0, stream>>>(src, dst, E, N, pos, csr);

    // 2. Layer 1: hw1 = x@W1 (+att dots), aggregate -> bufB (ELU applied)
    gemm_att<4><<<(N + 7) / 8, 128, 0, stream>>>(x, W1, a_src1, a_dst1, bufA, asrc1, adst1, N);
    agg<4><<<N, 128, 0, stream>>>(bufA, asrc1, adst1, offs, csr, b1, bufB, N);

    // 3. Layer 2: hw2 = y1@W2 (+att dots), aggregate -> bufB again (bufA freed after use)
    gemm_att<1><<<(N + 7) / 8, 128, 0, stream>>>(bufB, W2, a_src2, a_dst2, bufA, asrc2, adst2, N);
    agg<1><<<N, 128, 0, stream>>>(bufA, asrc2, adst2, offs, csr, b2, bufB, N);

    // 4. Final linear head
    lin_kernel<<<(N + 7) / 8, 64, 0, stream>>>(bufB, Wlin, blin, out, N, OUTC);
}

// Round 2
// 273.867 us; speedup vs baseline: 1.1376x; 1.1376x over previous
//
#include <hip/hip_runtime.h>

// ---------------- CSR build ----------------

__global__ void hist_kernel(const int* __restrict__ dst, int E, int N, int* __restrict__ deg) {
    int i = blockIdx.x * blockDim.x + threadIdx.x;
    int Etot = E + N;
    if (i < Etot) {
        int d = (i < E) ? dst[i] : (i - E);   // self-loops appended
        atomicAdd(&deg[d], 1);
    }
}

// Hierarchical scan: (1) per-block sums, (2) 1-wave scan of block sums, (3) apply.
__global__ void block_sums(const int* __restrict__ deg, int* __restrict__ bsum, int n) {
    __shared__ int s[256];
    int i = blockIdx.x * 256 + threadIdx.x;
    s[threadIdx.x] = (i < n) ? deg[i] : 0;
    __syncthreads();
    for (int off = 128; off > 0; off >>= 1) {
        if (threadIdx.x < off) s[threadIdx.x] += s[threadIdx.x + off];
        __syncthreads();
    }
    if (threadIdx.x == 0) bsum[blockIdx.x] = s[0];
}

// nb <= 64. One wave: inclusive shuffle-scan, write exclusive block offsets + total.
__global__ void scan_bsums(const int* __restrict__ bsum, int* __restrict__ boff,
                           int nb, int* __restrict__ offs, int n) {
    int j = threadIdx.x;  // 0..63
    int own = (j < nb) ? bsum[j] : 0;
    int v = own;
    for (int off = 1; off < 64; off <<= 1) {
        int t = __shfl_up(v, off);
        if (j >= off) v += t;
    }
    if (j < nb) boff[j] = v - own;          // exclusive prefix
    if (j == nb - 1) offs[n] = v;           // grand total
}

__global__ void scan_apply(const int* __restrict__ deg, const int* __restrict__ boff,
                           int* __restrict__ offs, int* __restrict__ pos, int n) {
    __shared__ int s[256];
    int i = blockIdx.x * 256 + threadIdx.x;
    int v = (i < n) ? deg[i] : 0;
    s[threadIdx.x] = v;
    __syncthreads();
    for (int off = 1; off < 256; off <<= 1) {
        int t = (threadIdx.x >= off) ? s[threadIdx.x - off] : 0;
        __syncthreads();
        s[threadIdx.x] += t;
        __syncthreads();
    }
    int excl = boff[blockIdx.x] + s[threadIdx.x] - v;
    if (i < n) { offs[i] = excl; pos[i] = excl; }
}

__global__ void scatter_kernel(const int* __restrict__ srcArr, const int* __restrict__ dstArr,
                               int E, int N, int* __restrict__ pos, int* __restrict__ csr_src) {
    int i = blockIdx.x * blockDim.x + threadIdx.x;
    int Etot = E + N;
    if (i < Etot) {
        int s, d;
        if (i < E) { s = srcArr[i]; d = dstArr[i]; }
        else       { s = d = i - E; }
        int p = atomicAdd(&pos[d], 1);
        csr_src[p] = s;
    }
}

// ---------------- GEMM (x @ W) + attention dot products ----------------
template <int H>
__global__ void gemm_att(const float* __restrict__ x, const float* __restrict__ W,
                         const float* __restrict__ a_src, const float* __restrict__ a_dst,
                         float* __restrict__ hw, float* __restrict__ asrc,
                         float* __restrict__ adst, int N) {
    const int NB = 8;
    int n0 = blockIdx.x * NB;
    int j = threadIdx.x;   // 0..127
    __shared__ float xr[NB][128];
    __shared__ float tmp[4];
    for (int r = 0; r < NB; r++) {
        int nn = n0 + r;
        xr[r][j] = (nn < N) ? x[nn * 128 + j] : 0.f;
    }
    __syncthreads();
    float acc[NB];
#pragma unroll
    for (int r = 0; r < NB; r++) acc[r] = 0.f;
    for (int k = 0; k < 128; k++) {
        float w = W[k * 128 + j];
#pragma unroll
        for (int r = 0; r < NB; r++) acc[r] += xr[r][k] * w;
    }
    const int dh = 128 / H;
    int h = j / dh;
    float as = a_src[j];
    float ad = a_dst[j];
    for (int r = 0; r < NB; r++) {
        int nn = n0 + r;
        if (nn < N) hw[nn * 128 + j] = acc[r];
        float vs = acc[r] * as;
        float vd = acc[r] * ad;
        if (H == 4) {
            for (int off = 16; off >= 1; off >>= 1) {
                vs += __shfl_xor(vs, off);
                vd += __shfl_xor(vd, off);
            }
            if ((j & 31) == 0 && nn < N) { asrc[nn * 4 + h] = vs; adst[nn * 4 + h] = vd; }
        } else {
            for (int off = 32; off >= 1; off >>= 1) {
                vs += __shfl_xor(vs, off);
                vd += __shfl_xor(vd, off);
            }
            if ((j & 63) == 0) { tmp[(j >> 6) * 2] = vs; tmp[(j >> 6) * 2 + 1] = vd; }
            __syncthreads();
            if (j == 0 && nn < N) { asrc[nn] = tmp[0] + tmp[2]; adst[nn] = tmp[1] + tmp[3]; }
            __syncthreads();
        }
    }
}

// ---------------- Fused attention softmax + aggregation, one block per dst node ----------------
// z computed via per-thread partials during exp staging (no divergent serial loop).
template <int H>
__global__ void agg(const float* __restrict__ hw, const float* __restrict__ asrc,
                    const float* __restrict__ adst, const int* __restrict__ offs,
                    const int* __restrict__ csr_src, const float* __restrict__ b,
                    float* __restrict__ y, int N) {
    int n = blockIdx.x;
    int j = threadIdx.x;  // 0..127
    int beg = offs[n], end = offs[n + 1];
    int deg = end - beg;
    __shared__ float pe[128 * H];
    __shared__ int se[128];
    __shared__ float adl[H];
    __shared__ float zred[2 * H];
    if (j < H) adl[j] = adst[n * H + j];
    const int dh = 128 / H;
    int h = j / dh;
    float accv = 0.f;
    float zp[H];
#pragma unroll
    for (int hh = 0; hh < H; hh++) zp[hh] = 0.f;
    for (int base = 0; base < deg; base += 128) {
        int cnt = min(128, deg - base);
        __syncthreads();  // previous chunk's reads done before overwrite
        if (j < cnt) {
            int s = csr_src[beg + base + j];
            se[j] = s;
#pragma unroll
            for (int hh = 0; hh < H; hh++) {
                float e = asrc[s * H + hh] + adl[hh];
                e = e > 0.f ? e : 0.2f * e;  // leaky_relu(0.2)
                float p = __expf(e);
                pe[j * H + hh] = p;
                zp[hh] += p;
            }
        }
        __syncthreads();
        for (int c = 0; c < cnt; c++) {
            accv += pe[c * H + h] * hw[se[c] * 128 + j];
        }
    }
    // reduce zp across 128 threads: wave shuffle + 2-wave LDS combine
#pragma unroll
    for (int hh = 0; hh < H; hh++) {
        float v = zp[hh];
        for (int off = 32; off >= 1; off >>= 1) v += __shfl_xor(v, off);
        if ((j & 63) == 0) zred[(j >> 6) * H + hh] = v;
    }
    __syncthreads();
    float z = zred[h] + zred[H + h];
    float res = accv / (z + 1e-16f) + b[j];
    y[n * 128 + j] = res > 0.f ? res : (__expf(res) - 1.0f);  // ELU
}

// ---------------- Final linear head (128 -> OUT) ----------------
__global__ void lin_kernel(const float* __restrict__ y2, const float* __restrict__ Wl,
                           const float* __restrict__ bl, float* __restrict__ out,
                           int N, int OUTC) {
    const int NB = 8;
    int n0 = blockIdx.x * NB;
    int j = threadIdx.x;  // 0..63
    __shared__ float r[NB][128];
    for (int rr = 0; rr < NB; rr++) {
        int nn = n0 + rr;
        r[rr][j]      = (nn < N) ? y2[nn * 128 + j] : 0.f;
        r[rr][j + 64] = (nn < N) ? y2[nn * 128 + j + 64] : 0.f;
    }
    __syncthreads();
    if (j < OUTC) {
        float acc[NB];
#pragma unroll
        for (int rr = 0; rr < NB; rr++) acc[rr] = bl[j];
        for (int k = 0; k < 128; k++) {
            float w = Wl[k * OUTC + j];
#pragma unroll
            for (int rr = 0; rr < NB; rr++) acc[rr] += r[rr][k] * w;
        }
        for (int rr = 0; rr < NB; rr++) {
            int nn = n0 + rr;
            if (nn < N) out[nn * OUTC + j] = acc[rr];
        }
    }
}

extern "C" void kernel_launch(void* const* d_in, const int* in_sizes, int n_in,
                              void* d_out, int out_size, void* d_ws, size_t ws_size,
                              hipStream_t stream) {
    const float* x       = (const float*)d_in[0];
    const int*   ei      = (const int*)d_in[1];
    const float* W1      = (const float*)d_in[2];
    const float* a_src1  = (const float*)d_in[3];
    const float* a_dst1  = (const float*)d_in[4];
    const float* b1      = (const float*)d_in[5];
    const float* W2      = (const float*)d_in[6];
    const float* a_src2  = (const float*)d_in[7];
    const float* a_dst2  = (const float*)d_in[8];
    const float* b2      = (const float*)d_in[9];
    const float* Wlin    = (const float*)d_in[10];
    const float* blin    = (const float*)d_in[11];
    float* out = (float*)d_out;

    const int N = in_sizes[0] / 128;     // 10000
    const int E = in_sizes[1] / 2;       // 640000
    const int OUTC = in_sizes[10] / 128; // 40
    const int Etot = E + N;
    const int* src = ei;
    const int* dst = ei + E;
    const int NBLK = (N + 255) / 256;    // 40 (must be <= 64 for scan_bsums)

    // workspace carve-up (256B aligned)
    char* w = (char*)d_ws;
    size_t off = 0;
    auto alloc = [&](size_t bytes) -> char* {
        char* p = w + off;
        off += (bytes + 255) & ~(size_t)255;
        return p;
    };
    int*   deg    = (int*)alloc((size_t)N * 4);
    int*   offs   = (int*)alloc((size_t)(N + 1) * 4);
    int*   pos    = (int*)alloc((size_t)N * 4);
    int*   csr    = (int*)alloc((size_t)Etot * 4);
    int*   bsum   = (int*)alloc((size_t)NBLK * 4);
    int*   boff   = (int*)alloc((size_t)NBLK * 4);
    float* bufA   = (float*)alloc((size_t)N * 128 * 4);
    float* bufB   = (float*)alloc((size_t)N * 128 * 4);
    float* asrc1  = (float*)alloc((size_t)N * 4 * 4);
    float* adst1  = (float*)alloc((size_t)N * 4 * 4);
    float* asrc2  = (float*)alloc((size_t)N * 4);
    float* adst2  = (float*)alloc((size_t)N * 4);
    (void)ws_size;

    // 1. CSR build (same graph reused for both layers)
    hipMemsetAsync(deg, 0, (size_t)N * 4, stream);
    hist_kernel<<<(Etot + 255) / 256, 256, 0, stream>>>(dst, E, N, deg);
    block_sums<<<NBLK, 256, 0, stream>>>(deg, bsum, N);
    scan_bsums<<<1, 64, 0, stream>>>(bsum, boff, NBLK, offs, N);
    scan_apply<<<NBLK, 256, 0, stream>>>(deg, boff, offs, pos, N);
    scatter_kernel<<<(Etot + 255) / 256, 256, 0, stream>>>(src, dst, E, N, pos, csr);

    // 2. Layer 1
    gemm_att<4><<<(N + 7) / 8, 128, 0, stream>>>(x, W1, a_src1, a_dst1, bufA, asrc1, adst1, N);
    agg<4><<<N, 128, 0, stream>>>(bufA, asrc1, adst1, offs, csr, b1, bufB, N);

    // 3. Layer 2
    gemm_att<1><<<(N + 7) / 8, 128, 0, stream>>>(bufB, W2, a_src2, a_dst2, bufA, asrc2, adst2, N);
    agg<1><<<N, 128, 0, stream>>>(bufA, asrc2, adst2, offs, csr, b2, bufB, N);

    // 4. Final linear head
    lin_kernel<<<(N + 7) / 8, 64, 0, stream>>>(bufB, Wlin, blin, out, N, OUTC);
}

// Round 3
// 245.112 us; speedup vs baseline: 1.2711x; 1.1173x over previous
//
#include <hip/hip_runtime.h>

// ---------------- CSR build (2-pass counting sort, single atomic pass) ----------------

// Pass 1: histogram AND per-edge rank in one atomic.
__global__ void hist_rank(const int* __restrict__ dst, int E, int N,
                          int* __restrict__ deg, int* __restrict__ rank) {
    int i = blockIdx.x * blockDim.x + threadIdx.x;
    int Etot = E + N;
    if (i < Etot) {
        int d = (i < E) ? dst[i] : (i - E);   // self-loops appended
        rank[i] = atomicAdd(&deg[d], 1);
    }
}

// Hierarchical scan: (1) per-block sums, (2) 1-wave scan of block sums, (3) apply.
__global__ void block_sums(const int* __restrict__ deg, int* __restrict__ bsum, int n) {
    __shared__ int s[256];
    int i = blockIdx.x * 256 + threadIdx.x;
    s[threadIdx.x] = (i < n) ? deg[i] : 0;
    __syncthreads();
    for (int off = 128; off > 0; off >>= 1) {
        if (threadIdx.x < off) s[threadIdx.x] += s[threadIdx.x + off];
        __syncthreads();
    }
    if (threadIdx.x == 0) bsum[blockIdx.x] = s[0];
}

// nb <= 64. One wave: inclusive shuffle-scan, write exclusive block offsets + total.
__global__ void scan_bsums(const int* __restrict__ bsum, int* __restrict__ boff,
                           int nb, int* __restrict__ offs, int n) {
    int j = threadIdx.x;  // 0..63
    int own = (j < nb) ? bsum[j] : 0;
    int v = own;
    for (int off = 1; off < 64; off <<= 1) {
        int t = __shfl_up(v, off);
        if (j >= off) v += t;
    }
    if (j < nb) boff[j] = v - own;          // exclusive prefix
    if (j == nb - 1) offs[n] = v;           // grand total
}

__global__ void scan_apply(const int* __restrict__ deg, const int* __restrict__ boff,
                           int* __restrict__ offs, int n) {
    __shared__ int s[256];
    int i = blockIdx.x * 256 + threadIdx.x;
    int v = (i < n) ? deg[i] : 0;
    s[threadIdx.x] = v;
    __syncthreads();
    for (int off = 1; off < 256; off <<= 1) {
        int t = (threadIdx.x >= off) ? s[threadIdx.x - off] : 0;
        __syncthreads();
        s[threadIdx.x] += t;
        __syncthreads();
    }
    if (i < n) offs[i] = boff[blockIdx.x] + s[threadIdx.x] - v;
}

// Pass 2: atomic-free permute.
__global__ void scatter2(const int* __restrict__ srcArr, const int* __restrict__ dstArr,
                         int E, int N, const int* __restrict__ offs,
                         const int* __restrict__ rank, int* __restrict__ csr_src) {
    int i = blockIdx.x * blockDim.x + threadIdx.x;
    int Etot = E + N;
    if (i < Etot) {
        int s, d;
        if (i < E) { s = srcArr[i]; d = dstArr[i]; }
        else       { s = d = i - E; }
        csr_src[offs[d] + rank[i]] = s;
    }
}

// ---------------- GEMM (x @ W) + attention dot products ----------------
template <int H>
__global__ void gemm_att(const float* __restrict__ x, const float* __restrict__ W,
                         const float* __restrict__ a_src, const float* __restrict__ a_dst,
                         float* __restrict__ hw, float* __restrict__ asrc,
                         float* __restrict__ adst, int N) {
    const int NB = 8;
    int n0 = blockIdx.x * NB;
    int j = threadIdx.x;   // 0..127
    __shared__ float xr[NB][128];
    __shared__ float tmp[4];
    for (int r = 0; r < NB; r++) {
        int nn = n0 + r;
        xr[r][j] = (nn < N) ? x[nn * 128 + j] : 0.f;
    }
    __syncthreads();
    float acc[NB];
#pragma unroll
    for (int r = 0; r < NB; r++) acc[r] = 0.f;
    for (int k = 0; k < 128; k++) {
        float w = W[k * 128 + j];
#pragma unroll
        for (int r = 0; r < NB; r++) acc[r] += xr[r][k] * w;
    }
    const int dh = 128 / H;
    int h = j / dh;
    float as = a_src[j];
    float ad = a_dst[j];
    for (int r = 0; r < NB; r++) {
        int nn = n0 + r;
        if (nn < N) hw[nn * 128 + j] = acc[r];
        float vs = acc[r] * as;
        float vd = acc[r] * ad;
        if (H == 4) {
            for (int off = 16; off >= 1; off >>= 1) {
                vs += __shfl_xor(vs, off);
                vd += __shfl_xor(vd, off);
            }
            if ((j & 31) == 0 && nn < N) { asrc[nn * 4 + h] = vs; adst[nn * 4 + h] = vd; }
        } else {
            for (int off = 32; off >= 1; off >>= 1) {
                vs += __shfl_xor(vs, off);
                vd += __shfl_xor(vd, off);
            }
            if ((j & 63) == 0) { tmp[(j >> 6) * 2] = vs; tmp[(j >> 6) * 2 + 1] = vd; }
            __syncthreads();
            if (j == 0 && nn < N) { asrc[nn] = tmp[0] + tmp[2]; adst[nn] = tmp[1] + tmp[3]; }
            __syncthreads();
        }
    }
}

// ---------------- Fused attention softmax + aggregation ----------------
// One block (128 threads = 4 edge-groups x 32 lanes) per dst node.
// Each lane owns 4 columns (float4); group g processes edges g, g+4, ...
template <int H>
__global__ void agg(const float* __restrict__ hw, const float* __restrict__ asrc,
                    const float* __restrict__ adst, const int* __restrict__ offs,
                    const int* __restrict__ csr_src, const float* __restrict__ b,
                    float* __restrict__ y, int N) {
    int n = blockIdx.x;
    int t = threadIdx.x;   // 0..127
    int g = t >> 5;        // edge group 0..3
    int lane = t & 31;     // column group: columns lane*4 .. lane*4+3
    int beg = offs[n], deg = offs[n + 1] - beg;
    __shared__ float pe[128 * H];
    __shared__ int se[128];
    __shared__ float adl[H];
    __shared__ float red[4 * 128];
    __shared__ float zred[2 * H];
    if (t < H) adl[t] = adst[n * H + t];
    const int dh = 128 / H;
    int hcol = (lane * 4) / dh;        // head of this lane's 4 columns (all same head)
    float4 acc = make_float4(0.f, 0.f, 0.f, 0.f);
    float zp[H];
#pragma unroll
    for (int hh = 0; hh < H; hh++) zp[hh] = 0.f;
    for (int base = 0; base < deg; base += 128) {
        int cnt = min(128, deg - base);
        __syncthreads();  // previous chunk's reads done before overwrite
        if (t < cnt) {
            int s = csr_src[beg + base + t];
            se[t] = s;
#pragma unroll
            for (int hh = 0; hh < H; hh++) {
                float e = asrc[s * H + hh] + adl[hh];
                e = e > 0.f ? e : 0.2f * e;  // leaky_relu(0.2)
                float p = __expf(e);
                pe[t * H + hh] = p;
                zp[hh] += p;
            }
        }
        __syncthreads();
        for (int c = g; c < cnt; c += 4) {
            int s = se[c];
            float p = pe[c * H + hcol];
            float4 v = *(const float4*)&hw[s * 128 + lane * 4];
            acc.x += p * v.x; acc.y += p * v.y; acc.z += p * v.z; acc.w += p * v.w;
        }
    }
    // combine the 4 edge-groups' column partials via LDS
    ((float4*)&red[g * 128])[lane] = acc;
    // reduce zp across 128 threads: wave shuffle + 2-wave LDS combine
#pragma unroll
    for (int hh = 0; hh < H; hh++) {
        float v = zp[hh];
        for (int off = 32; off >= 1; off >>= 1) v += __shfl_xor(v, off);
        if ((t & 63) == 0) zred[(t >> 6) * H + hh] = v;
    }
    __syncthreads();
    float total = red[t] + red[128 + t] + red[256 + t] + red[384 + t];
    int h = t / dh;
    float z = zred[h] + zred[H + h];
    float res = total / (z + 1e-16f) + b[t];
    y[n * 128 + t] = res > 0.f ? res : (__expf(res) - 1.0f);  // ELU
}

// ---------------- Final linear head (128 -> OUT) ----------------
__global__ void lin_kernel(const float* __restrict__ y2, const float* __restrict__ Wl,
                           const float* __restrict__ bl, float* __restrict__ out,
                           int N, int OUTC) {
    const int NB = 8;
    int n0 = blockIdx.x * NB;
    int j = threadIdx.x;  // 0..63
    __shared__ float r[NB][128];
    for (int rr = 0; rr < NB; rr++) {
        int nn = n0 + rr;
        r[rr][j]      = (nn < N) ? y2[nn * 128 + j] : 0.f;
        r[rr][j + 64] = (nn < N) ? y2[nn * 128 + j + 64] : 0.f;
    }
    __syncthreads();
    if (j < OUTC) {
        float acc[NB];
#pragma unroll
        for (int rr = 0; rr < NB; rr++) acc[rr] = bl[j];
        for (int k = 0; k < 128; k++) {
            float w = Wl[k * OUTC + j];
#pragma unroll
            for (int rr = 0; rr < NB; rr++) acc[rr] += r[rr][k] * w;
        }
        for (int rr = 0; rr < NB; rr++) {
            int nn = n0 + rr;
            if (nn < N) out[nn * OUTC + j] = acc[rr];
        }
    }
}

extern "C" void kernel_launch(void* const* d_in, const int* in_sizes, int n_in,
                              void* d_out, int out_size, void* d_ws, size_t ws_size,
                              hipStream_t stream) {
    const float* x       = (const float*)d_in[0];
    const int*   ei      = (const int*)d_in[1];
    const float* W1      = (const float*)d_in[2];
    const float* a_src1  = (const float*)d_in[3];
    const float* a_dst1  = (const float*)d_in[4];
    const float* b1      = (const float*)d_in[5];
    const float* W2      = (const float*)d_in[6];
    const float* a_src2  = (const float*)d_in[7];
    const float* a_dst2  = (const float*)d_in[8];
    const float* b2      = (const float*)d_in[9];
    const float* Wlin    = (const float*)d_in[10];
    const float* blin    = (const float*)d_in[11];
    float* out = (float*)d_out;

    const int N = in_sizes[0] / 128;     // 10000
    const int E = in_sizes[1] / 2;       // 640000
    const int OUTC = in_sizes[10] / 128; // 40
    const int Etot = E + N;
    const int* src = ei;
    const int* dst = ei + E;
    const int NBLK = (N + 255) / 256;    // 40 (must be <= 64 for scan_bsums)

    // workspace carve-up (256B aligned)
    char* w = (char*)d_ws;
    size_t off = 0;
    auto alloc = [&](size_t bytes) -> char* {
        char* p = w + off;
        off += (bytes + 255) & ~(size_t)255;
        return p;
    };
    int*   deg    = (int*)alloc((size_t)N * 4);
    int*   offs   = (int*)alloc((size_t)(N + 1) * 4);
    int*   rank   = (int*)alloc((size_t)Etot * 4);
    int*   csr    = (int*)alloc((size_t)Etot * 4);
    int*   bsum   = (int*)alloc((size_t)NBLK * 4);
    int*   boff   = (int*)alloc((size_t)NBLK * 4);
    float* bufA   = (float*)alloc((size_t)N * 128 * 4);
    float* bufB   = (float*)alloc((size_t)N * 128 * 4);
    float* asrc1  = (float*)alloc((size_t)N * 4 * 4);
    float* adst1  = (float*)alloc((size_t)N * 4 * 4);
    float* asrc2  = (float*)alloc((size_t)N * 4);
    float* adst2  = (float*)alloc((size_t)N * 4);
    (void)ws_size;

    // 1. CSR build (one atomic pass + scan + atomic-free permute)
    hipMemsetAsync(deg, 0, (size_t)N * 4, stream);
    hist_rank<<<(Etot + 255) / 256, 256, 0, stream>>>(dst, E, N, deg, rank);
    block_sums<<<NBLK, 256, 0, stream>>>(deg, bsum, N);
    scan_bsums<<<1, 64, 0, stream>>>(bsum, boff, NBLK, offs, N);
    scan_apply<<<NBLK, 256, 0, stream>>>(deg, boff, offs, N);
    scatter2<<<(Etot + 255) / 256, 256, 0, stream>>>(src, dst, E, N, offs, rank, csr);

    // 2. Layer 1
    gemm_att<4><<<(N + 7) / 8, 128, 0, stream>>>(x, W1, a_src1, a_dst1, bufA, asrc1, adst1, N);
    agg<4><<<N, 128, 0, stream>>>(bufA, asrc1, adst1, offs, csr, b1, bufB, N);

    // 3. Layer 2
    gemm_att<1><<<(N + 7) / 8, 128, 0, stream>>>(bufB, W2, a_src2, a_dst2, bufA, asrc2, adst2, N);
    agg<1><<<N, 128, 0, stream>>>(bufA, asrc2, adst2, offs, csr, b2, bufB, N);

    // 4. Final linear head
    lin_kernel<<<(N + 7) / 8, 64, 0, stream>>>(bufB, Wlin, blin, out, N, OUTC);
}